// Round 4
// baseline (1034.829 us; speedup 1.0000x reference)
//
#include <hip/hip_runtime.h>

// FullAttention fwd: BH=32, T=2048, D=128, fp32 in/out, key_padding_mask (True=masked).
// Flash-style: 4 waves x 32 q-rows = 128 q/block, KVBLK=64, bf16 MFMA 16x16x32.
// Swapped QK^T (mfma(K,Q)) => softmax lane-local; P in-register feeds PV A-operand;
// V staged TRANSPOSED in LDS (Vt[d][kv]) with conflict-free swizzle ((d^(d>>2))&15)<<3.
// QK^T hi/lo bf16 split (3 MFMAs) for fp32-grade logits. Reg-staged async double
// buffering: tile t+1 global loads issued before compute of tile t (T14).
// Mask dtype (bool bytes vs int32) detected in-kernel.

#define BHN  32
#define TSEQ 2048
#define DDIM 128
#define QB   128   // q rows per block
#define WQ   32    // q rows per wave
#define KB   64    // kv rows per tile
#define NKT  (TSEQ / KB)

typedef __attribute__((ext_vector_type(4))) float f32x4;
typedef __attribute__((ext_vector_type(8))) short s16x8;
typedef __attribute__((ext_vector_type(4))) short s16x4;

__device__ __forceinline__ short f2bf(float x) {
    unsigned u = __float_as_uint(x);
    unsigned r = (u + 0x7FFFu + ((u >> 16) & 1u)) >> 16;
    return (short)r;
}
__device__ __forceinline__ float bf2f(short b) {
    return __uint_as_float(((unsigned)(unsigned short)b) << 16);
}
// Vt swizzle: conflict-free for per-d scalar writes (d=4s+j) AND per-d0 8B reads
// (d=16db+q16). XOR in bits [3:6] only -> 8B alignment preserved.
__device__ __forceinline__ unsigned vswz(int d, int kv) {
    return ((unsigned)((d * KB + kv) * 2)) ^ ((unsigned)((d ^ (d >> 2)) & 15) << 3);
}

__global__ __launch_bounds__(256, 2)
void attn_fwd(const float* __restrict__ Qg, const float* __restrict__ Kg,
              const float* __restrict__ Vg, const unsigned char* __restrict__ Mg,
              float* __restrict__ Og)
{
    __shared__ __align__(16) unsigned short Klds[KB * DDIM];  // 16KB K hi, XOR (row&7)<<4
    __shared__ __align__(16) unsigned short Klo [KB * DDIM];  // 16KB K lo, same swizzle
    __shared__ __align__(16) unsigned short Vt  [DDIM * KB];  // 16KB V^T (d,kv), vswz
    __shared__ float biasLds[KB];
    __shared__ int mflag;

    const int tid  = threadIdx.x;
    const int lane = tid & 63;
    const int wave = tid >> 6;
    const int q16  = lane & 15;
    const int hi   = lane >> 4;

    const int bh    = blockIdx.x;
    const int qbase = blockIdx.y * QB + wave * WQ;

    const float scale = 0.088388347648318447f; // 1/sqrt(128)

    const float* Qp = Qg + ((size_t)bh * TSEQ + qbase) * DDIM;
    const float* Kp = Kg + (size_t)bh * TSEQ * DDIM;
    const float* Vp = Vg + (size_t)bh * TSEQ * DDIM;

    // ---- mask layout detection (probe first 2KB; valid under both layouts) ----
    if (tid == 0) mflag = 0;
    __syncthreads();
    {
        int f = 0;
#pragma unroll
        for (int j = 0; j < 8; ++j) {
            const int idx = tid * 8 + j;
            if ((idx & 3) != 0 && Mg[idx] != 0) f = 1;
        }
        if (f) atomicOr(&mflag, 1);
    }
    __syncthreads();
    const int isByte = mflag;   // block-uniform

    // ---- Q fragments (hi/lo): lane holds Q[16qt+q16][32c+8hi+i]*scale ----
    s16x8 qhi[2][4], qlo[2][4];
#pragma unroll
    for (int qt = 0; qt < 2; ++qt) {
        const float* qrow = Qp + (size_t)(qt * 16 + q16) * DDIM;
#pragma unroll
        for (int c = 0; c < 4; ++c) {
            const int d0 = 32 * c + 8 * hi;
            float4 a = *reinterpret_cast<const float4*>(qrow + d0);
            float4 b = *reinterpret_cast<const float4*>(qrow + d0 + 4);
            float x[8] = {a.x, a.y, a.z, a.w, b.x, b.y, b.z, b.w};
            s16x8 fh, fl;
#pragma unroll
            for (int i = 0; i < 8; ++i) {
                const float xs = x[i] * scale;
                const short h = f2bf(xs);
                fh[i] = h;
                fl[i] = f2bf(xs - bf2f(h));
            }
            qhi[qt][c] = fh;
            qlo[qt][c] = fl;
        }
    }

    f32x4 o[2][8];
#pragma unroll
    for (int qt = 0; qt < 2; ++qt)
#pragma unroll
        for (int db = 0; db < 8; ++db)
            o[qt][db] = (f32x4){0.f, 0.f, 0.f, 0.f};
    float mrun[2] = {-1e30f, -1e30f};
    float lrun[2] = {0.f, 0.f};

    // staging assignment: thread covers rows srow+8p, d = sd..sd+3
    const int srow = tid >> 5;
    const int sd   = (tid & 31) * 4;

    // ---- prologue: load tile 0 into registers ----
    float4 kreg[8], vreg[8];
    int mreg = 0;
#pragma unroll
    for (int p = 0; p < 8; ++p) {
        const int row = srow + p * 8;
        kreg[p] = *reinterpret_cast<const float4*>(Kp + (size_t)row * DDIM + sd);
        vreg[p] = *reinterpret_cast<const float4*>(Vp + (size_t)row * DDIM + sd);
    }
    if (tid < KB) {
        const size_t mi = (size_t)bh * TSEQ + tid;
        mreg = isByte ? (int)Mg[mi] : ((const int*)Mg)[mi];
    }

    for (int kt = 0; kt < NKT; ++kt) {
        __syncthreads();   // previous tile's LDS readers done
        // ---- STORE tile kt from registers (convert f32 -> bf16 hi/lo) ----
        if (tid < KB) biasLds[tid] = mreg ? -1e30f : 0.0f;
#pragma unroll
        for (int p = 0; p < 8; ++p) {
            const int row = srow + p * 8;
            float kx[4] = {kreg[p].x, kreg[p].y, kreg[p].z, kreg[p].w};
            float vx[4] = {vreg[p].x, vreg[p].y, vreg[p].z, vreg[p].w};
            s16x4 kh4, kl4;
#pragma unroll
            for (int j = 0; j < 4; ++j) {
                const short h = f2bf(kx[j]);
                kh4[j] = h;
                kl4[j] = f2bf(kx[j] - bf2f(h));
            }
            const unsigned ka = ((unsigned)(row * 256 + sd * 2)) ^ ((unsigned)(row & 7) << 4);
            *reinterpret_cast<s16x4*>(reinterpret_cast<char*>(Klds) + ka) = kh4;
            *reinterpret_cast<s16x4*>(reinterpret_cast<char*>(Klo)  + ka) = kl4;
#pragma unroll
            for (int j = 0; j < 4; ++j)
                *reinterpret_cast<unsigned short*>(reinterpret_cast<char*>(Vt) + vswz(sd + j, row)) =
                    (unsigned short)f2bf(vx[j]);
        }
        // ---- issue tile kt+1 global loads (results used after compute => latency hidden) ----
        if (kt + 1 < NKT) {
            const int kv0n = (kt + 1) * KB;
#pragma unroll
            for (int p = 0; p < 8; ++p) {
                const int row = kv0n + srow + p * 8;
                kreg[p] = *reinterpret_cast<const float4*>(Kp + (size_t)row * DDIM + sd);
                vreg[p] = *reinterpret_cast<const float4*>(Vp + (size_t)row * DDIM + sd);
            }
            if (tid < KB) {
                const size_t mi = (size_t)bh * TSEQ + kv0n + tid;
                mreg = isByte ? (int)Mg[mi] : ((const int*)Mg)[mi];
            }
        }
        __syncthreads();

        // ---- S^T = K . Q^T : D[kv][q], acc initialized with mask bias ----
        f32x4 st[2][4];
#pragma unroll
        for (int t = 0; t < 4; ++t) {
            f32x4 binit;
#pragma unroll
            for (int r = 0; r < 4; ++r) binit[r] = biasLds[16 * t + 4 * hi + r];
            st[0][t] = binit;
            st[1][t] = binit;
        }
        __builtin_amdgcn_s_setprio(1);
#pragma unroll
        for (int t = 0; t < 4; ++t) {
#pragma unroll
            for (int c = 0; c < 4; ++c) {
                const unsigned ka =
                    ((unsigned)((16 * t + q16) * 256 + (32 * c + 8 * hi) * 2)) ^
                    ((unsigned)(q16 & 7) << 4);
                s16x8 kh = *reinterpret_cast<const s16x8*>(reinterpret_cast<char*>(Klds) + ka);
                s16x8 kl = *reinterpret_cast<const s16x8*>(reinterpret_cast<char*>(Klo)  + ka);
                st[0][t] = __builtin_amdgcn_mfma_f32_16x16x32_bf16(kh, qhi[0][c], st[0][t], 0, 0, 0);
                st[1][t] = __builtin_amdgcn_mfma_f32_16x16x32_bf16(kh, qhi[1][c], st[1][t], 0, 0, 0);
                st[0][t] = __builtin_amdgcn_mfma_f32_16x16x32_bf16(kh, qlo[0][c], st[0][t], 0, 0, 0);
                st[1][t] = __builtin_amdgcn_mfma_f32_16x16x32_bf16(kh, qlo[1][c], st[1][t], 0, 0, 0);
                st[0][t] = __builtin_amdgcn_mfma_f32_16x16x32_bf16(kl, qhi[0][c], st[0][t], 0, 0, 0);
                st[1][t] = __builtin_amdgcn_mfma_f32_16x16x32_bf16(kl, qhi[1][c], st[1][t], 0, 0, 0);
            }
        }
        __builtin_amdgcn_s_setprio(0);

        // ---- online softmax (lane-local: q = q16 in group qt, kv = 16t + 4hi + r) ----
        s16x8 pf[2][2];
        float resc[2];
#pragma unroll
        for (int qt = 0; qt < 2; ++qt) {
            float mx = st[qt][0][0];
#pragma unroll
            for (int t = 0; t < 4; ++t)
#pragma unroll
                for (int r = 0; r < 4; ++r)
                    mx = fmaxf(mx, st[qt][t][r]);
            mx = fmaxf(mx, __shfl_xor(mx, 16));
            mx = fmaxf(mx, __shfl_xor(mx, 32));
            const float mnew = fmaxf(mrun[qt], mx);
            const float rs   = __expf(mrun[qt] - mnew);
            mrun[qt] = mnew;
            resc[qt] = rs;
            float ps = 0.f;
            float pv[4][4];
#pragma unroll
            for (int t = 0; t < 4; ++t)
#pragma unroll
                for (int r = 0; r < 4; ++r) {
                    const float e = __expf(st[qt][t][r] - mnew);
                    pv[t][r] = e;
                    ps += e;
                }
            ps += __shfl_xor(ps, 16);
            ps += __shfl_xor(ps, 32);
            lrun[qt] = lrun[qt] * rs + ps;
            // pack P (A-operand): frag h slot i: kv = 32h + 16*(i>=4) + 4hi + (i&3)
#pragma unroll
            for (int h = 0; h < 2; ++h) {
                s16x8 f;
#pragma unroll
                for (int r = 0; r < 4; ++r) {
                    f[r]     = f2bf(pv[2 * h][r]);
                    f[r + 4] = f2bf(pv[2 * h + 1][r]);
                }
                pf[qt][h] = f;
            }
        }
        // rescale O: row q' = 4hi + r needs stat from lane (lane&48)|q'
#pragma unroll
        for (int qt = 0; qt < 2; ++qt)
#pragma unroll
            for (int r = 0; r < 4; ++r) {
                const int src = (lane & 48) | (4 * hi + r);
                const float rr = __shfl(resc[qt], src);
#pragma unroll
                for (int db = 0; db < 8; ++db)
                    o[qt][db][r] *= rr;
            }

        // ---- PV: o[qt][db] += P . V ; B-frag slot i holds
        //      V[kv = 32h + 16*(i>=4) + 4hi + (i&3)][d = 16db + q16] (matches P-pack) ----
        __builtin_amdgcn_s_setprio(1);
#pragma unroll
        for (int db = 0; db < 8; ++db) {
            const int d = db * 16 + q16;
            s16x8 vfrag[2];
#pragma unroll
            for (int h = 0; h < 2; ++h) {
                s16x4 lo4 = *reinterpret_cast<const s16x4*>(
                    reinterpret_cast<const char*>(Vt) + vswz(d, 32 * h + 4 * hi));
                s16x4 hi4 = *reinterpret_cast<const s16x4*>(
                    reinterpret_cast<const char*>(Vt) + vswz(d, 32 * h + 16 + 4 * hi));
                s16x8 vv;
                vv[0] = lo4[0]; vv[1] = lo4[1]; vv[2] = lo4[2]; vv[3] = lo4[3];
                vv[4] = hi4[0]; vv[5] = hi4[1]; vv[6] = hi4[2]; vv[7] = hi4[3];
                vfrag[h] = vv;
            }
            o[0][db] = __builtin_amdgcn_mfma_f32_16x16x32_bf16(pf[0][0], vfrag[0], o[0][db], 0, 0, 0);
            o[0][db] = __builtin_amdgcn_mfma_f32_16x16x32_bf16(pf[0][1], vfrag[1], o[0][db], 0, 0, 0);
            o[1][db] = __builtin_amdgcn_mfma_f32_16x16x32_bf16(pf[1][0], vfrag[0], o[1][db], 0, 0, 0);
            o[1][db] = __builtin_amdgcn_mfma_f32_16x16x32_bf16(pf[1][1], vfrag[1], o[1][db], 0, 0, 0);
        }
        __builtin_amdgcn_s_setprio(0);
    }

    // ---- epilogue: normalize by l and store (rows q' = 16qt + 4hi + r) ----
    float* Op = Og + ((size_t)bh * TSEQ + qbase) * DDIM;
#pragma unroll
    for (int qt = 0; qt < 2; ++qt)
#pragma unroll
        for (int r = 0; r < 4; ++r) {
            const int src = (lane & 48) | (4 * hi + r);
            const float inv = 1.0f / __shfl(lrun[qt], src);
            const int qrow = qt * 16 + 4 * hi + r;
#pragma unroll
            for (int db = 0; db < 8; ++db)
                Op[(size_t)qrow * DDIM + db * 16 + q16] = o[qt][db][r] * inv;
        }
}

extern "C" void kernel_launch(void* const* d_in, const int* in_sizes, int n_in,
                              void* d_out, int out_size, void* d_ws, size_t ws_size,
                              hipStream_t stream) {
    const float* q = (const float*)d_in[0];
    const float* k = (const float*)d_in[1];
    const float* v = (const float*)d_in[2];
    const unsigned char* m = (const unsigned char*)d_in[3];
    float* out = (float*)d_out;
    dim3 grid(BHN, TSEQ / QB);   // same-head q-blocks land on one XCD (ids differ by 32)
    dim3 block(256);
    attn_fwd<<<grid, block, 0, stream>>>(q, k, v, m, out);
}

// Round 5
// 483.440 us; speedup vs baseline: 2.1406x; 2.1406x over previous
//
#include <hip/hip_runtime.h>
#include <hip/hip_bf16.h>

// FullAttention fwd: BH=32, T=2048, D=128, fp32 in/out, key_padding_mask (True=masked).
// Flash-style: 4 waves x 32 q-rows = 128 q/block, KVBLK=64, bf16 MFMA 16x16x32.
// Swapped QK^T (mfma(K,Q)) => softmax lane-local; P in-register feeds PV A-operand.
// V stored transposed in LDS with kv-bit-permute sigma so each PV B-fragment is ONE
// ds_read_b128; 16B-granule XOR swizzle ((d^(d>>3))&7)<<4 keeps it bank-spread and
// 16B-aligned. QK^T hi/lo bf16 split (3 MFMA passes) for fp32-grade logits.
// Packed f32->bf16 conversion via __float22bfloat162_rn (v_cvt_pk_bf16_f32).
// Loads issued between barriers (R3 placement) - NO reg double-buffer (R4 spilled).

#define BHN  32
#define TSEQ 2048
#define DDIM 128
#define QB   128   // q rows per block
#define WQ   32    // q rows per wave
#define KB   64    // kv rows per tile
#define NKT  (TSEQ / KB)

typedef __attribute__((ext_vector_type(4))) float f32x4;
typedef __attribute__((ext_vector_type(8))) short s16x8;
typedef __attribute__((ext_vector_type(4))) short s16x4;

__device__ __forceinline__ short f2bf(float x) {
    unsigned u = __float_as_uint(x);
    unsigned r = (u + 0x7FFFu + ((u >> 16) & 1u)) >> 16;
    return (short)r;
}
__device__ __forceinline__ float bf2f(short b) {
    return __uint_as_float(((unsigned)(unsigned short)b) << 16);
}
// packed RNE f32x2 -> bf16x2 (lo = a, hi = b); compiler emits v_cvt_pk_bf16_f32
__device__ __forceinline__ unsigned pk2bf(float a, float b) {
    union { __hip_bfloat162 h; unsigned u; } cv;
    cv.h = __float22bfloat162_rn(make_float2(a, b));
    return cv.u;
}
// kv bit-permute: maps kv=32h+16u+4hi+r -> 32h+8hi+4u+r, so the 8 slots a PV lane
// needs (fixed h,hi; u,r varying) are contiguous -> single b128 read.
__device__ __forceinline__ int sigma(int kv) {
    return (kv & 3) | (((kv >> 4) & 1) << 2) | (((kv >> 2) & 3) << 3) | (kv & 32);
}
// Vt byte address: 16B-granule XOR swizzle, preserves 16B alignment for b128 reads.
__device__ __forceinline__ unsigned vaddr(int d, int kvp) {
    return ((unsigned)((d * KB + kvp) * 2)) ^ (((unsigned)((d ^ (d >> 3)) & 7)) << 4);
}

__global__ __launch_bounds__(256, 2)
void attn_fwd(const float* __restrict__ Qg, const float* __restrict__ Kg,
              const float* __restrict__ Vg, const unsigned char* __restrict__ Mg,
              float* __restrict__ Og)
{
    __shared__ __align__(16) unsigned short Klds[KB * DDIM];  // 16KB K hi, XOR (row&7)<<4
    __shared__ __align__(16) unsigned short Klo [KB * DDIM];  // 16KB K lo, same swizzle
    __shared__ __align__(16) unsigned short Vt  [DDIM * KB];  // 16KB V^T (d, sigma(kv))
    __shared__ float biasLds[KB];
    __shared__ int mflag;

    const int tid  = threadIdx.x;
    const int lane = tid & 63;
    const int wave = tid >> 6;
    const int q16  = lane & 15;
    const int hi   = lane >> 4;

    const int bh    = blockIdx.x;
    const int qbase = blockIdx.y * QB + wave * WQ;

    const float scale = 0.088388347648318447f; // 1/sqrt(128)

    const float* Qp = Qg + ((size_t)bh * TSEQ + qbase) * DDIM;
    const float* Kp = Kg + (size_t)bh * TSEQ * DDIM;
    const float* Vp = Vg + (size_t)bh * TSEQ * DDIM;

    // ---- mask layout detection (probe first 2KB; valid under both layouts) ----
    if (tid == 0) mflag = 0;
    __syncthreads();
    {
        int f = 0;
#pragma unroll
        for (int j = 0; j < 8; ++j) {
            const int idx = tid * 8 + j;
            if ((idx & 3) != 0 && Mg[idx] != 0) f = 1;
        }
        if (f) atomicOr(&mflag, 1);
    }
    __syncthreads();
    const int isByte = mflag;   // block-uniform

    // ---- Q fragments (hi/lo): lane holds Q[16qt+q16][32c+8hi+i]*scale ----
    s16x8 qhi[2][4], qlo[2][4];
#pragma unroll
    for (int qt = 0; qt < 2; ++qt) {
        const float* qrow = Qp + (size_t)(qt * 16 + q16) * DDIM;
#pragma unroll
        for (int c = 0; c < 4; ++c) {
            const int d0 = 32 * c + 8 * hi;
            float4 a = *reinterpret_cast<const float4*>(qrow + d0);
            float4 b = *reinterpret_cast<const float4*>(qrow + d0 + 4);
            float x[8] = {a.x, a.y, a.z, a.w, b.x, b.y, b.z, b.w};
            s16x8 fh, fl;
#pragma unroll
            for (int i = 0; i < 8; ++i) {
                const float xs = x[i] * scale;
                const short h = f2bf(xs);
                fh[i] = h;
                fl[i] = f2bf(xs - bf2f(h));
            }
            qhi[qt][c] = fh;
            qlo[qt][c] = fl;
        }
    }

    f32x4 o[2][8];
#pragma unroll
    for (int qt = 0; qt < 2; ++qt)
#pragma unroll
        for (int db = 0; db < 8; ++db)
            o[qt][db] = (f32x4){0.f, 0.f, 0.f, 0.f};
    float mrun[2] = {-1e30f, -1e30f};
    float lrun[2] = {0.f, 0.f};

    // staging assignment: thread covers rows srow+8p, d = sd..sd+3
    const int srow = tid >> 5;
    const int sd   = (tid & 31) * 4;

    for (int kt = 0; kt < NKT; ++kt) {
        const int kv0 = kt * KB;
        __syncthreads();   // previous tile's LDS readers done
        if (tid < KB) {
            const size_t mi = (size_t)bh * TSEQ + kv0 + tid;
            const int mv = isByte ? (int)Mg[mi] : ((const int*)Mg)[mi];
            biasLds[tid] = mv ? -1e30f : 0.0f;
        }
#pragma unroll
        for (int p = 0; p < 8; ++p) {
            const int row = srow + p * 8;
            float4 kf = *reinterpret_cast<const float4*>(Kp + (size_t)(kv0 + row) * DDIM + sd);
            float4 vf = *reinterpret_cast<const float4*>(Vp + (size_t)(kv0 + row) * DDIM + sd);
            // K hi/lo via packed cvt
            union { s16x4 v; unsigned u[2]; } kh, kl;
            kh.u[0] = pk2bf(kf.x, kf.y);
            kh.u[1] = pk2bf(kf.z, kf.w);
            const float r0 = kf.x - __uint_as_float(kh.u[0] << 16);
            const float r1 = kf.y - __uint_as_float(kh.u[0] & 0xffff0000u);
            const float r2 = kf.z - __uint_as_float(kh.u[1] << 16);
            const float r3 = kf.w - __uint_as_float(kh.u[1] & 0xffff0000u);
            kl.u[0] = pk2bf(r0, r1);
            kl.u[1] = pk2bf(r2, r3);
            const unsigned ka = ((unsigned)(row * 256 + sd * 2)) ^ ((unsigned)(row & 7) << 4);
            *reinterpret_cast<s16x4*>(reinterpret_cast<char*>(Klds) + ka) = kh.v;
            *reinterpret_cast<s16x4*>(reinterpret_cast<char*>(Klo)  + ka) = kl.v;
            // V: scalar 2B stores into (d, sigma(kv)) layout
            const int kvp = sigma(row);
            const unsigned v01 = pk2bf(vf.x, vf.y);
            const unsigned v23 = pk2bf(vf.z, vf.w);
            *reinterpret_cast<unsigned short*>(reinterpret_cast<char*>(Vt) + vaddr(sd + 0, kvp)) =
                (unsigned short)(v01 & 0xffffu);
            *reinterpret_cast<unsigned short*>(reinterpret_cast<char*>(Vt) + vaddr(sd + 1, kvp)) =
                (unsigned short)(v01 >> 16);
            *reinterpret_cast<unsigned short*>(reinterpret_cast<char*>(Vt) + vaddr(sd + 2, kvp)) =
                (unsigned short)(v23 & 0xffffu);
            *reinterpret_cast<unsigned short*>(reinterpret_cast<char*>(Vt) + vaddr(sd + 3, kvp)) =
                (unsigned short)(v23 >> 16);
        }
        __syncthreads();

        // ---- S^T = K . Q^T : D[kv][q], acc initialized with mask bias ----
        f32x4 st[2][4];
#pragma unroll
        for (int t = 0; t < 4; ++t) {
            f32x4 binit;
#pragma unroll
            for (int r = 0; r < 4; ++r) binit[r] = biasLds[16 * t + 4 * hi + r];
            st[0][t] = binit;
            st[1][t] = binit;
        }
        __builtin_amdgcn_s_setprio(1);
#pragma unroll
        for (int t = 0; t < 4; ++t) {
#pragma unroll
            for (int c = 0; c < 4; ++c) {
                const unsigned ka =
                    ((unsigned)((16 * t + q16) * 256 + (32 * c + 8 * hi) * 2)) ^
                    ((unsigned)(q16 & 7) << 4);
                s16x8 kh = *reinterpret_cast<const s16x8*>(reinterpret_cast<char*>(Klds) + ka);
                s16x8 kl = *reinterpret_cast<const s16x8*>(reinterpret_cast<char*>(Klo)  + ka);
                st[0][t] = __builtin_amdgcn_mfma_f32_16x16x32_bf16(kh, qhi[0][c], st[0][t], 0, 0, 0);
                st[1][t] = __builtin_amdgcn_mfma_f32_16x16x32_bf16(kh, qhi[1][c], st[1][t], 0, 0, 0);
                st[0][t] = __builtin_amdgcn_mfma_f32_16x16x32_bf16(kh, qlo[0][c], st[0][t], 0, 0, 0);
                st[1][t] = __builtin_amdgcn_mfma_f32_16x16x32_bf16(kh, qlo[1][c], st[1][t], 0, 0, 0);
                st[0][t] = __builtin_amdgcn_mfma_f32_16x16x32_bf16(kl, qhi[0][c], st[0][t], 0, 0, 0);
                st[1][t] = __builtin_amdgcn_mfma_f32_16x16x32_bf16(kl, qhi[1][c], st[1][t], 0, 0, 0);
            }
        }
        __builtin_amdgcn_s_setprio(0);

        // ---- online softmax (lane-local: q = q16 in group qt, kv = 16t + 4hi + r) ----
        s16x8 pf[2][2];
        float resc[2];
#pragma unroll
        for (int qt = 0; qt < 2; ++qt) {
            float mx = st[qt][0][0];
#pragma unroll
            for (int t = 0; t < 4; ++t)
#pragma unroll
                for (int r = 0; r < 4; ++r)
                    mx = fmaxf(mx, st[qt][t][r]);
            mx = fmaxf(mx, __shfl_xor(mx, 16));
            mx = fmaxf(mx, __shfl_xor(mx, 32));
            const float mnew = fmaxf(mrun[qt], mx);
            const float rs   = __expf(mrun[qt] - mnew);
            mrun[qt] = mnew;
            resc[qt] = rs;
            float ps = 0.f;
            float pv[4][4];
#pragma unroll
            for (int t = 0; t < 4; ++t)
#pragma unroll
                for (int r = 0; r < 4; ++r) {
                    const float e = __expf(st[qt][t][r] - mnew);
                    pv[t][r] = e;
                    ps += e;
                }
            ps += __shfl_xor(ps, 16);
            ps += __shfl_xor(ps, 32);
            lrun[qt] = lrun[qt] * rs + ps;
            // pack P (A-operand): frag h slot i: kv = 32h + 16*(i>=4) + 4hi + (i&3)
#pragma unroll
            for (int h = 0; h < 2; ++h) {
                union { s16x8 v; unsigned u[4]; } f;
                f.u[0] = pk2bf(pv[2 * h][0], pv[2 * h][1]);
                f.u[1] = pk2bf(pv[2 * h][2], pv[2 * h][3]);
                f.u[2] = pk2bf(pv[2 * h + 1][0], pv[2 * h + 1][1]);
                f.u[3] = pk2bf(pv[2 * h + 1][2], pv[2 * h + 1][3]);
                pf[qt][h] = f.v;
            }
        }
        // rescale O: row q' = 4hi + r needs stat from lane (lane&48)|q'
#pragma unroll
        for (int qt = 0; qt < 2; ++qt)
#pragma unroll
            for (int r = 0; r < 4; ++r) {
                const int src = (lane & 48) | (4 * hi + r);
                const float rr = __shfl(resc[qt], src);
#pragma unroll
                for (int db = 0; db < 8; ++db)
                    o[qt][db][r] *= rr;
            }

        // ---- PV: o[qt][db] += P . V ; B-frag = ONE b128 read (sigma layout) ----
        __builtin_amdgcn_s_setprio(1);
#pragma unroll
        for (int db = 0; db < 8; ++db) {
            const int d = db * 16 + q16;
            s16x8 vfrag[2];
#pragma unroll
            for (int h = 0; h < 2; ++h)
                vfrag[h] = *reinterpret_cast<const s16x8*>(
                    reinterpret_cast<const char*>(Vt) + vaddr(d, 32 * h + 8 * hi));
            o[0][db] = __builtin_amdgcn_mfma_f32_16x16x32_bf16(pf[0][0], vfrag[0], o[0][db], 0, 0, 0);
            o[0][db] = __builtin_amdgcn_mfma_f32_16x16x32_bf16(pf[0][1], vfrag[1], o[0][db], 0, 0, 0);
            o[1][db] = __builtin_amdgcn_mfma_f32_16x16x32_bf16(pf[1][0], vfrag[0], o[1][db], 0, 0, 0);
            o[1][db] = __builtin_amdgcn_mfma_f32_16x16x32_bf16(pf[1][1], vfrag[1], o[1][db], 0, 0, 0);
        }
        __builtin_amdgcn_s_setprio(0);
    }

    // ---- epilogue: normalize by l and store (rows q' = 16qt + 4hi + r) ----
    float* Op = Og + ((size_t)bh * TSEQ + qbase) * DDIM;
#pragma unroll
    for (int qt = 0; qt < 2; ++qt)
#pragma unroll
        for (int r = 0; r < 4; ++r) {
            const int src = (lane & 48) | (4 * hi + r);
            const float inv = 1.0f / __shfl(lrun[qt], src);
            const int qrow = qt * 16 + 4 * hi + r;
#pragma unroll
            for (int db = 0; db < 8; ++db)
                Op[(size_t)qrow * DDIM + db * 16 + q16] = o[qt][db][r] * inv;
        }
}

extern "C" void kernel_launch(void* const* d_in, const int* in_sizes, int n_in,
                              void* d_out, int out_size, void* d_ws, size_t ws_size,
                              hipStream_t stream) {
    const float* q = (const float*)d_in[0];
    const float* k = (const float*)d_in[1];
    const float* v = (const float*)d_in[2];
    const unsigned char* m = (const unsigned char*)d_in[3];
    float* out = (float*)d_out;
    dim3 grid(BHN, TSEQ / QB);   // same-head q-blocks land on one XCD (ids differ by 32)
    dim3 block(256);
    attn_fwd<<<grid, block, 0, stream>>>(q, k, v, m, out);
}

// Round 7
// 295.708 us; speedup vs baseline: 3.4995x; 1.6349x over previous
//
#include <hip/hip_runtime.h>
#include <hip/hip_bf16.h>

// FullAttention fwd: BH=32, T=2048, D=128, fp32 in/out, key_padding_mask (True=masked).
// R6 structure: 512 thr (8 waves x 32 q = 256 q/block), grid (32,8) = 256 blocks = 1/CU.
// Double-buffered LDS (96KB), ONE barrier/iter: issue loads(t+1) -> compute(t) ->
// cvt+write(t+1) -> barrier. Only 32 VGPR held across compute; launch_bounds(512,2)
// caps VGPR at 256 (R4 spilled at 64 held under a 128 cap).
// Staging: each thread owns a kv-QUAD (4 rows x 4 d) so V-transpose writes are b64 of
// sigma-consecutive elements; row-assignment bit-designed so in-wave groups differ in
// kvp bit2 -> writes spread all 32 banks. QK^T hi/lo bf16 (fp32-grade logits), swapped
// operands => softmax lane-local; P in-register feeds PV A-operand; V^T sigma layout
// gives one b128 read per PV B-fragment.

#define BHN  32
#define TSEQ 2048
#define DDIM 128
#define QB   256   // q rows per block
#define WQ   32    // q rows per wave
#define KB   64    // kv rows per tile
#define NKT  (TSEQ / KB)

typedef __attribute__((ext_vector_type(4))) float f32x4;
typedef __attribute__((ext_vector_type(8))) short s16x8;
typedef __attribute__((ext_vector_type(4))) short s16x4;

__device__ __forceinline__ short f2bf(float x) {
    unsigned u = __float_as_uint(x);
    unsigned r = (u + 0x7FFFu + ((u >> 16) & 1u)) >> 16;
    return (short)r;
}
__device__ __forceinline__ float bf2f(short b) {
    return __uint_as_float(((unsigned)(unsigned short)b) << 16);
}
// packed RNE f32x2 -> bf16x2 (lo = a, hi = b); emits v_cvt_pk_bf16_f32
__device__ __forceinline__ unsigned pk2bf(float a, float b) {
    union { __hip_bfloat162 h; unsigned u; } cv;
    cv.h = __float22bfloat162_rn(make_float2(a, b));
    return cv.u;
}
// K byte addr (row-major [64][128] bf16, m214 XOR swizzle)
__device__ __forceinline__ unsigned kaddr(int row, int d) {
    return ((unsigned)(row * 256 + d * 2)) ^ ((unsigned)(row & 7) << 4);
}
// V^T byte addr: (d, kvp) with 16B-granule XOR swizzle (preserves b64/b128 alignment)
__device__ __forceinline__ unsigned vaddr(int d, int kvp) {
    return ((unsigned)(d * 128 + kvp * 2)) ^ (((unsigned)((d ^ (d >> 3)) & 7)) << 4);
}

__global__ __launch_bounds__(512, 2)
void attn_fwd(const float* __restrict__ Qg, const float* __restrict__ Kg,
              const float* __restrict__ Vg, const unsigned char* __restrict__ Mg,
              float* __restrict__ Og)
{
    __shared__ __align__(16) unsigned short Khi[2][KB * DDIM]; // 2x16KB
    __shared__ __align__(16) unsigned short Klo[2][KB * DDIM]; // 2x16KB
    __shared__ __align__(16) unsigned short Vt [2][DDIM * KB]; // 2x16KB (d, sigma(kv))
    __shared__ float biasLds[2][KB];
    __shared__ int mflag;

    const int tid  = threadIdx.x;
    const int lane = tid & 63;
    const int wave = tid >> 6;
    const int q16  = lane & 15;
    const int hi   = lane >> 4;

    const int bh    = blockIdx.x;
    const int qbase = blockIdx.y * QB + wave * WQ;

    const float scale = 0.088388347648318447f; // 1/sqrt(128)

    const float* Qp = Qg + ((size_t)bh * TSEQ + qbase) * DDIM;
    const float* Kp = Kg + (size_t)bh * TSEQ * DDIM;
    const float* Vp = Vg + (size_t)bh * TSEQ * DDIM;

    // ---- mask layout detection (probe first 2KB; valid under both layouts) ----
    if (tid == 0) mflag = 0;
    __syncthreads();
    {
        int f = 0;
#pragma unroll
        for (int j = 0; j < 4; ++j) {
            const int idx = tid * 4 + j;
            if ((idx & 3) != 0 && Mg[idx] != 0) f = 1;
        }
        if (f) atomicOr(&mflag, 1);
    }
    __syncthreads();
    const int isByte = mflag;   // block-uniform

    // ---- Q fragments (hi/lo): lane holds Q[16qt+q16][32c+8hi+i]*scale ----
    s16x8 qhi[2][4], qlo[2][4];
#pragma unroll
    for (int qt = 0; qt < 2; ++qt) {
        const float* qrow = Qp + (size_t)(qt * 16 + q16) * DDIM;
#pragma unroll
        for (int c = 0; c < 4; ++c) {
            const int d0 = 32 * c + 8 * hi;
            f32x4 a = *reinterpret_cast<const f32x4*>(qrow + d0);
            f32x4 b = *reinterpret_cast<const f32x4*>(qrow + d0 + 4);
            s16x8 fh, fl;
#pragma unroll
            for (int i = 0; i < 8; ++i) {
                const float xs = (i < 4 ? a[i] : b[i - 4]) * scale;
                const short h = f2bf(xs);
                fh[i] = h;
                fl[i] = f2bf(xs - bf2f(h));
            }
            qhi[qt][c] = fh;
            qlo[qt][c] = fl;
        }
    }

    f32x4 o[2][8];
#pragma unroll
    for (int qt = 0; qt < 2; ++qt)
#pragma unroll
        for (int db = 0; db < 8; ++db)
            o[qt][db] = (f32x4){0.f, 0.f, 0.f, 0.f};
    float mrun[2] = {-1e30f, -1e30f};
    float lrun[2] = {0.f, 0.f};

    // ---- staging assignment: thread owns kv-quad rb..rb+3 at d = sd..sd+3 ----
    // qrow bijective over tid>>5 in 0..15; in-wave groups (lanes 0-31 vs 32-63)
    // differ in qrow bit2 -> kvp bit2 -> addr bit3 -> full 32-bank spread.
    const int sd   = (tid & 31) * 4;
    const int qrw  = (((tid >> 5) & 1) << 2) | ((tid >> 6) & 3) | (((tid >> 8) & 1) << 3);
    const int rb   = qrw * 4;
    // sigma base of the quad: sigma(4m+r) = kvpb + r
    const int kvpb = (((qrw >> 2) & 1) << 2) | ((qrw & 3) << 3) | (((qrw >> 3) & 1) << 5);

    f32x4 kreg[4], vreg[4];
    int mreg = 0;

#define LOAD_TILE(kv0)                                                              \
    {                                                                               \
        _Pragma("unroll")                                                           \
        for (int r = 0; r < 4; ++r) {                                               \
            kreg[r] = *reinterpret_cast<const f32x4*>(Kp + (size_t)((kv0) + rb + r) * DDIM + sd); \
            vreg[r] = *reinterpret_cast<const f32x4*>(Vp + (size_t)((kv0) + rb + r) * DDIM + sd); \
        }                                                                           \
        if (tid < KB) {                                                             \
            const size_t mi = (size_t)bh * TSEQ + (kv0) + tid;                      \
            mreg = isByte ? (int)Mg[mi] : ((const int*)Mg)[mi];                     \
        }                                                                           \
    }

#define STORE_TILE(b)                                                               \
    {                                                                               \
        if (tid < KB) biasLds[b][tid] = mreg ? -1e30f : 0.0f;                       \
        char* khb = reinterpret_cast<char*>(&Khi[b][0]);                            \
        char* klb = reinterpret_cast<char*>(&Klo[b][0]);                            \
        char* vtb = reinterpret_cast<char*>(&Vt[b][0]);                             \
        _Pragma("unroll")                                                           \
        for (int r = 0; r < 4; ++r) {                                               \
            union { s16x4 v; unsigned u[2]; } kh, kl;                               \
            kh.u[0] = pk2bf(kreg[r][0], kreg[r][1]);                                \
            kh.u[1] = pk2bf(kreg[r][2], kreg[r][3]);                                \
            const float r0 = kreg[r][0] - __uint_as_float(kh.u[0] << 16);           \
            const float r1 = kreg[r][1] - __uint_as_float(kh.u[0] & 0xffff0000u);   \
            const float r2 = kreg[r][2] - __uint_as_float(kh.u[1] << 16);           \
            const float r3 = kreg[r][3] - __uint_as_float(kh.u[1] & 0xffff0000u);   \
            kl.u[0] = pk2bf(r0, r1);                                                \
            kl.u[1] = pk2bf(r2, r3);                                                \
            const unsigned ka = kaddr(rb + r, sd);                                  \
            *reinterpret_cast<s16x4*>(khb + ka) = kh.v;                             \
            *reinterpret_cast<s16x4*>(klb + ka) = kl.v;                             \
        }                                                                           \
        _Pragma("unroll")                                                           \
        for (int j = 0; j < 4; ++j) {                                               \
            union { s16x4 v; unsigned u[2]; } vv;                                   \
            vv.u[0] = pk2bf(vreg[0][j], vreg[1][j]);                                \
            vv.u[1] = pk2bf(vreg[2][j], vreg[3][j]);                                \
            *reinterpret_cast<s16x4*>(vtb + vaddr(sd + j, kvpb)) = vv.v;            \
        }                                                                           \
    }

    // ---- prologue: tile 0 ----
    LOAD_TILE(0);
    STORE_TILE(0);
    __syncthreads();

    for (int kt = 0; kt < NKT; ++kt) {
        const int cur = kt & 1;
        // issue next tile's global loads; they land during compute below
        if (kt + 1 < NKT) LOAD_TILE((kt + 1) * KB);

        const char* khb = reinterpret_cast<const char*>(&Khi[cur][0]);
        const char* klb = reinterpret_cast<const char*>(&Klo[cur][0]);
        const char* vtb = reinterpret_cast<const char*>(&Vt[cur][0]);

        // ---- S^T = K . Q^T : D[kv][q], acc initialized with mask bias ----
        f32x4 st[2][4];
#pragma unroll
        for (int t = 0; t < 4; ++t) {
            f32x4 binit;
#pragma unroll
            for (int r = 0; r < 4; ++r) binit[r] = biasLds[cur][16 * t + 4 * hi + r];
            st[0][t] = binit;
            st[1][t] = binit;
        }
        __builtin_amdgcn_s_setprio(1);
#pragma unroll
        for (int t = 0; t < 4; ++t) {
#pragma unroll
            for (int c = 0; c < 4; ++c) {
                const unsigned ka = kaddr(16 * t + q16, 32 * c + 8 * hi);
                s16x8 kh = *reinterpret_cast<const s16x8*>(khb + ka);
                s16x8 kl = *reinterpret_cast<const s16x8*>(klb + ka);
                st[0][t] = __builtin_amdgcn_mfma_f32_16x16x32_bf16(kh, qhi[0][c], st[0][t], 0, 0, 0);
                st[1][t] = __builtin_amdgcn_mfma_f32_16x16x32_bf16(kh, qhi[1][c], st[1][t], 0, 0, 0);
                st[0][t] = __builtin_amdgcn_mfma_f32_16x16x32_bf16(kh, qlo[0][c], st[0][t], 0, 0, 0);
                st[1][t] = __builtin_amdgcn_mfma_f32_16x16x32_bf16(kh, qlo[1][c], st[1][t], 0, 0, 0);
                st[0][t] = __builtin_amdgcn_mfma_f32_16x16x32_bf16(kl, qhi[0][c], st[0][t], 0, 0, 0);
                st[1][t] = __builtin_amdgcn_mfma_f32_16x16x32_bf16(kl, qhi[1][c], st[1][t], 0, 0, 0);
            }
        }
        __builtin_amdgcn_s_setprio(0);

        // ---- online softmax (lane-local: q = q16 in group qt, kv = 16t + 4hi + r) ----
        s16x8 pf[2][2];
        float resc[2];
#pragma unroll
        for (int qt = 0; qt < 2; ++qt) {
            float mx = st[qt][0][0];
#pragma unroll
            for (int t = 0; t < 4; ++t)
#pragma unroll
                for (int r = 0; r < 4; ++r)
                    mx = fmaxf(mx, st[qt][t][r]);
            mx = fmaxf(mx, __shfl_xor(mx, 16));
            mx = fmaxf(mx, __shfl_xor(mx, 32));
            const float mnew = fmaxf(mrun[qt], mx);
            const float rs   = __expf(mrun[qt] - mnew);
            mrun[qt] = mnew;
            resc[qt] = rs;
            float ps = 0.f;
            float pv[4][4];
#pragma unroll
            for (int t = 0; t < 4; ++t)
#pragma unroll
                for (int r = 0; r < 4; ++r) {
                    const float e = __expf(st[qt][t][r] - mnew);
                    pv[t][r] = e;
                    ps += e;
                }
            ps += __shfl_xor(ps, 16);
            ps += __shfl_xor(ps, 32);
            lrun[qt] = lrun[qt] * rs + ps;
            // pack P (A-operand): frag h slot i: kv = 32h + 16*(i>=4) + 4hi + (i&3)
#pragma unroll
            for (int h = 0; h < 2; ++h) {
                union { s16x8 v; unsigned u[4]; } f;
                f.u[0] = pk2bf(pv[2 * h][0], pv[2 * h][1]);
                f.u[1] = pk2bf(pv[2 * h][2], pv[2 * h][3]);
                f.u[2] = pk2bf(pv[2 * h + 1][0], pv[2 * h + 1][1]);
                f.u[3] = pk2bf(pv[2 * h + 1][2], pv[2 * h + 1][3]);
                pf[qt][h] = f.v;
            }
        }
        // rescale O: row q' = 4hi + r needs stat from lane (lane&48)|q'
#pragma unroll
        for (int qt = 0; qt < 2; ++qt)
#pragma unroll
            for (int r = 0; r < 4; ++r) {
                const int src = (lane & 48) | (4 * hi + r);
                const float rr = __shfl(resc[qt], src);
#pragma unroll
                for (int db = 0; db < 8; ++db)
                    o[qt][db][r] *= rr;
            }

        // ---- PV: o[qt][db] += P . V ; B-frag = ONE b128 read (sigma layout) ----
        __builtin_amdgcn_s_setprio(1);
#pragma unroll
        for (int db = 0; db < 8; ++db) {
            const int d = db * 16 + q16;
            s16x8 vfrag[2];
#pragma unroll
            for (int h = 0; h < 2; ++h)
                vfrag[h] = *reinterpret_cast<const s16x8*>(vtb + vaddr(d, 32 * h + 8 * hi));
            o[0][db] = __builtin_amdgcn_mfma_f32_16x16x32_bf16(pf[0][0], vfrag[0], o[0][db], 0, 0, 0);
            o[0][db] = __builtin_amdgcn_mfma_f32_16x16x32_bf16(pf[0][1], vfrag[1], o[0][db], 0, 0, 0);
            o[1][db] = __builtin_amdgcn_mfma_f32_16x16x32_bf16(pf[1][0], vfrag[0], o[1][db], 0, 0, 0);
            o[1][db] = __builtin_amdgcn_mfma_f32_16x16x32_bf16(pf[1][1], vfrag[1], o[1][db], 0, 0, 0);
        }
        __builtin_amdgcn_s_setprio(0);

        // ---- write next tile to the other buffer; single barrier per iteration ----
        if (kt + 1 < NKT) STORE_TILE(cur ^ 1);
        __syncthreads();
    }

    // ---- epilogue: normalize by l and store (rows q' = 16qt + 4hi + r) ----
    float* Op = Og + ((size_t)bh * TSEQ + qbase) * DDIM;
#pragma unroll
    for (int qt = 0; qt < 2; ++qt)
#pragma unroll
        for (int r = 0; r < 4; ++r) {
            const int src = (lane & 48) | (4 * hi + r);
            const float inv = 1.0f / __shfl(lrun[qt], src);
            const int qrow = qt * 16 + 4 * hi + r;
#pragma unroll
            for (int db = 0; db < 8; ++db)
                Op[(size_t)qrow * DDIM + db * 16 + q16] = o[qt][db][r] * inv;
        }
}

extern "C" void kernel_launch(void* const* d_in, const int* in_sizes, int n_in,
                              void* d_out, int out_size, void* d_ws, size_t ws_size,
                              hipStream_t stream) {
    const float* q = (const float*)d_in[0];
    const float* k = (const float*)d_in[1];
    const float* v = (const float*)d_in[2];
    const unsigned char* m = (const unsigned char*)d_in[3];
    float* out = (float*)d_out;
    dim3 grid(BHN, TSEQ / QB);   // (32, 8) = 256 blocks = 1 per CU; same-head blocks share an XCD
    dim3 block(512);
    attn_fwd<<<grid, block, 0, stream>>>(q, k, v, m, out);
}

// Round 9
// 209.011 us; speedup vs baseline: 4.9511x; 1.4148x over previous
//
#include <hip/hip_runtime.h>
#include <hip/hip_fp16.h>

// FullAttention fwd: BH=32, T=2048, D=128, fp32 in/out, key_padding_mask (True=masked).
// R8: FP16 single-pass (replaces R7's bf16 hi/lo). mfma_f32_16x16x32_f16 @ bf16 rate;
// fp16 rel-err 2.4e-4 -> logit tails ~3e-3, well under the 1.05e-2 threshold.
// 512 thr (8 waves x 32 q = 256 q/block), grid (32,8) = 256 blocks = 1/CU.
// Double-buffered LDS (65KB), ONE barrier/iter: issue loads(t+1) -> compute(t) ->
// cvt+write(t+1) -> barrier. Swapped QK^T (mfma(K,Q)) => softmax lane-local; P
// in-register feeds PV A-operand; V^T sigma layout gives one b128 read per PV B-frag.

#define BHN  32
#define TSEQ 2048
#define DDIM 128
#define QB   256   // q rows per block
#define WQ   32    // q rows per wave
#define KB   64    // kv rows per tile
#define NKT  (TSEQ / KB)

typedef __attribute__((ext_vector_type(4))) float    f32x4;
typedef __attribute__((ext_vector_type(8))) _Float16 f16x8;
typedef __attribute__((ext_vector_type(4))) _Float16 f16x4;

// K byte addr (row-major [64][128] f16, m214 XOR swizzle)
__device__ __forceinline__ unsigned kaddr(int row, int d) {
    return ((unsigned)(row * 256 + d * 2)) ^ ((unsigned)(row & 7) << 4);
}
// V^T byte addr: (d, kvp) with 16B-granule XOR swizzle (preserves b64/b128 alignment)
__device__ __forceinline__ unsigned vaddr(int d, int kvp) {
    return ((unsigned)(d * 128 + kvp * 2)) ^ (((unsigned)((d ^ (d >> 3)) & 7)) << 4);
}

__global__ __launch_bounds__(512, 2)
void attn_fwd(const float* __restrict__ Qg, const float* __restrict__ Kg,
              const float* __restrict__ Vg, const unsigned char* __restrict__ Mg,
              float* __restrict__ Og)
{
    __shared__ __align__(16) unsigned short Kh[2][KB * DDIM]; // 2x16KB f16, XOR-swizzled
    __shared__ __align__(16) unsigned short Vt[2][DDIM * KB]; // 2x16KB f16 (d, sigma(kv))
    __shared__ float biasLds[2][KB];
    __shared__ int mflag;

    const int tid  = threadIdx.x;
    const int lane = tid & 63;
    const int wave = tid >> 6;
    const int q16  = lane & 15;
    const int hi   = lane >> 4;

    const int bh    = blockIdx.x;
    const int qbase = blockIdx.y * QB + wave * WQ;

    const float scale = 0.088388347648318447f; // 1/sqrt(128)

    const float* Qp = Qg + ((size_t)bh * TSEQ + qbase) * DDIM;
    const float* Kp = Kg + (size_t)bh * TSEQ * DDIM;
    const float* Vp = Vg + (size_t)bh * TSEQ * DDIM;

    // ---- mask layout detection (probe first 2KB; valid under both layouts) ----
    if (tid == 0) mflag = 0;
    __syncthreads();
    {
        int f = 0;
#pragma unroll
        for (int j = 0; j < 4; ++j) {
            const int idx = tid * 4 + j;
            if ((idx & 3) != 0 && Mg[idx] != 0) f = 1;
        }
        if (f) atomicOr(&mflag, 1);
    }
    __syncthreads();
    const int isByte = mflag;   // block-uniform

    // ---- Q fragments (fp16): lane holds Q[16qt+q16][32c+8hi+i]*scale ----
    f16x8 qf[2][4];
#pragma unroll
    for (int qt = 0; qt < 2; ++qt) {
        const float* qrow = Qp + (size_t)(qt * 16 + q16) * DDIM;
#pragma unroll
        for (int c = 0; c < 4; ++c) {
            const int d0 = 32 * c + 8 * hi;
            f32x4 a = *reinterpret_cast<const f32x4*>(qrow + d0);
            f32x4 b = *reinterpret_cast<const f32x4*>(qrow + d0 + 4);
            f16x8 f;
#pragma unroll
            for (int i = 0; i < 8; ++i)
                f[i] = (_Float16)((i < 4 ? a[i] : b[i - 4]) * scale);
            qf[qt][c] = f;
        }
    }

    f32x4 o[2][8];
#pragma unroll
    for (int qt = 0; qt < 2; ++qt)
#pragma unroll
        for (int db = 0; db < 8; ++db)
            o[qt][db] = (f32x4){0.f, 0.f, 0.f, 0.f};
    float mrun[2] = {-1e30f, -1e30f};
    float lrun[2] = {0.f, 0.f};

    // ---- staging assignment: thread owns kv-quad rb..rb+3 at d = sd..sd+3 ----
    // qrw bijective over tid>>5 in 0..15; in-wave groups differ in kvp bit2 ->
    // addr bit3 -> V-transpose b64 writes spread across all 32 banks.
    const int sd   = (tid & 31) * 4;
    const int qrw  = (((tid >> 5) & 1) << 2) | ((tid >> 6) & 3) | (((tid >> 8) & 1) << 3);
    const int rb   = qrw * 4;
    // sigma base of the quad: sigma(4m+r) = kvpb + r
    const int kvpb = (((qrw >> 2) & 1) << 2) | ((qrw & 3) << 3) | (((qrw >> 3) & 1) << 5);

    f32x4 kreg[4], vreg[4];
    int mreg = 0;

#define LOAD_TILE(kv0)                                                              \
    {                                                                               \
        _Pragma("unroll")                                                           \
        for (int r = 0; r < 4; ++r) {                                               \
            kreg[r] = *reinterpret_cast<const f32x4*>(Kp + (size_t)((kv0) + rb + r) * DDIM + sd); \
            vreg[r] = *reinterpret_cast<const f32x4*>(Vp + (size_t)((kv0) + rb + r) * DDIM + sd); \
        }                                                                           \
        if (tid < KB) {                                                             \
            const size_t mi = (size_t)bh * TSEQ + (kv0) + tid;                      \
            mreg = isByte ? (int)Mg[mi] : ((const int*)Mg)[mi];                     \
        }                                                                           \
    }

#define STORE_TILE(b)                                                               \
    {                                                                               \
        if (tid < KB) biasLds[b][tid] = mreg ? -1e30f : 0.0f;                       \
        char* khb = reinterpret_cast<char*>(&Kh[b][0]);                             \
        char* vtb = reinterpret_cast<char*>(&Vt[b][0]);                             \
        _Pragma("unroll")                                                           \
        for (int r = 0; r < 4; ++r) {                                               \
            f16x4 k4;                                                               \
            k4[0] = (_Float16)kreg[r][0]; k4[1] = (_Float16)kreg[r][1];             \
            k4[2] = (_Float16)kreg[r][2]; k4[3] = (_Float16)kreg[r][3];             \
            *reinterpret_cast<f16x4*>(khb + kaddr(rb + r, sd)) = k4;                \
        }                                                                           \
        _Pragma("unroll")                                                           \
        for (int j = 0; j < 4; ++j) {                                               \
            f16x4 v4;                                                               \
            v4[0] = (_Float16)vreg[0][j]; v4[1] = (_Float16)vreg[1][j];             \
            v4[2] = (_Float16)vreg[2][j]; v4[3] = (_Float16)vreg[3][j];             \
            *reinterpret_cast<f16x4*>(vtb + vaddr(sd + j, kvpb)) = v4;              \
        }                                                                           \
    }

    // ---- prologue: tile 0 ----
    LOAD_TILE(0);
    STORE_TILE(0);
    __syncthreads();

    for (int kt = 0; kt < NKT; ++kt) {
        const int cur = kt & 1;
        // issue next tile's global loads; they land during compute below
        if (kt + 1 < NKT) LOAD_TILE((kt + 1) * KB);

        const char* khb = reinterpret_cast<const char*>(&Kh[cur][0]);
        const char* vtb = reinterpret_cast<const char*>(&Vt[cur][0]);

        // ---- S^T = K . Q^T : D[kv][q], acc initialized with mask bias ----
        f32x4 st[2][4];
#pragma unroll
        for (int t = 0; t < 4; ++t) {
            f32x4 binit;
#pragma unroll
            for (int r = 0; r < 4; ++r) binit[r] = biasLds[cur][16 * t + 4 * hi + r];
            st[0][t] = binit;
            st[1][t] = binit;
        }
        __builtin_amdgcn_s_setprio(1);
#pragma unroll
        for (int t = 0; t < 4; ++t) {
#pragma unroll
            for (int c = 0; c < 4; ++c) {
                const unsigned ka = kaddr(16 * t + q16, 32 * c + 8 * hi);
                f16x8 kf = *reinterpret_cast<const f16x8*>(khb + ka);
                st[0][t] = __builtin_amdgcn_mfma_f32_16x16x32_f16(kf, qf[0][c], st[0][t], 0, 0, 0);
                st[1][t] = __builtin_amdgcn_mfma_f32_16x16x32_f16(kf, qf[1][c], st[1][t], 0, 0, 0);
            }
        }
        __builtin_amdgcn_s_setprio(0);

        // ---- online softmax (lane-local: q = q16 in group qt, kv = 16t + 4hi + r) ----
        f16x8 pf[2][2];
        float resc[2];
#pragma unroll
        for (int qt = 0; qt < 2; ++qt) {
            float mx = st[qt][0][0];
#pragma unroll
            for (int t = 0; t < 4; ++t)
#pragma unroll
                for (int r = 0; r < 4; ++r)
                    mx = fmaxf(mx, st[qt][t][r]);
            mx = fmaxf(mx, __shfl_xor(mx, 16));
            mx = fmaxf(mx, __shfl_xor(mx, 32));
            const float mnew = fmaxf(mrun[qt], mx);
            const float rs   = __expf(mrun[qt] - mnew);
            mrun[qt] = mnew;
            resc[qt] = rs;
            float ps = 0.f;
            float pv[4][4];
#pragma unroll
            for (int t = 0; t < 4; ++t)
#pragma unroll
                for (int r = 0; r < 4; ++r) {
                    const float e = __expf(st[qt][t][r] - mnew);
                    pv[t][r] = e;
                    ps += e;
                }
            ps += __shfl_xor(ps, 16);
            ps += __shfl_xor(ps, 32);
            lrun[qt] = lrun[qt] * rs + ps;
            // pack P (A-operand): frag h slot i: kv = 32h + 16*(i>=4) + 4hi + (i&3)
#pragma unroll
            for (int h = 0; h < 2; ++h) {
                f16x8 f;
#pragma unroll
                for (int r = 0; r < 4; ++r) {
                    f[r]     = (_Float16)pv[2 * h][r];
                    f[r + 4] = (_Float16)pv[2 * h + 1][r];
                }
                pf[qt][h] = f;
            }
        }
        // rescale O: row q' = 4hi + r needs stat from lane (lane&48)|q'
#pragma unroll
        for (int qt = 0; qt < 2; ++qt)
#pragma unroll
            for (int r = 0; r < 4; ++r) {
                const int src = (lane & 48) | (4 * hi + r);
                const float rr = __shfl(resc[qt], src);
#pragma unroll
                for (int db = 0; db < 8; ++db)
                    o[qt][db][r] *= rr;
            }

        // ---- PV: o[qt][db] += P . V ; B-frag = ONE b128 read (sigma layout) ----
        __builtin_amdgcn_s_setprio(1);
#pragma unroll
        for (int db = 0; db < 8; ++db) {
            const int d = db * 16 + q16;
            f16x8 vfrag[2];
#pragma unroll
            for (int h = 0; h < 2; ++h)
                vfrag[h] = *reinterpret_cast<const f16x8*>(vtb + vaddr(d, 32 * h + 8 * hi));
            o[0][db] = __builtin_amdgcn_mfma_f32_16x16x32_f16(pf[0][0], vfrag[0], o[0][db], 0, 0, 0);
            o[0][db] = __builtin_amdgcn_mfma_f32_16x16x32_f16(pf[0][1], vfrag[1], o[0][db], 0, 0, 0);
            o[1][db] = __builtin_amdgcn_mfma_f32_16x16x32_f16(pf[1][0], vfrag[0], o[1][db], 0, 0, 0);
            o[1][db] = __builtin_amdgcn_mfma_f32_16x16x32_f16(pf[1][1], vfrag[1], o[1][db], 0, 0, 0);
        }
        __builtin_amdgcn_s_setprio(0);

        // ---- write next tile to the other buffer; single barrier per iteration ----
        if (kt + 1 < NKT) STORE_TILE(cur ^ 1);
        __syncthreads();
    }

    // ---- epilogue: normalize by l and store (rows q' = 16qt + 4hi + r) ----
    float* Op = Og + ((size_t)bh * TSEQ + qbase) * DDIM;
#pragma unroll
    for (int qt = 0; qt < 2; ++qt)
#pragma unroll
        for (int r = 0; r < 4; ++r) {
            const int src = (lane & 48) | (4 * hi + r);
            const float inv = 1.0f / __shfl(lrun[qt], src);
            const int qrow = qt * 16 + 4 * hi + r;
#pragma unroll
            for (int db = 0; db < 8; ++db)
                Op[(size_t)qrow * DDIM + db * 16 + q16] = o[qt][db][r] * inv;
        }
}

extern "C" void kernel_launch(void* const* d_in, const int* in_sizes, int n_in,
                              void* d_out, int out_size, void* d_ws, size_t ws_size,
                              hipStream_t stream) {
    const float* q = (const float*)d_in[0];
    const float* k = (const float*)d_in[1];
    const float* v = (const float*)d_in[2];
    const unsigned char* m = (const unsigned char*)d_in[3];
    float* out = (float*)d_out;
    dim3 grid(BHN, TSEQ / QB);   // (32, 8) = 256 blocks = 1 per CU; same-head blocks share an XCD
    dim3 block(512);
    attn_fwd<<<grid, block, 0, stream>>>(q, k, v, m, out);
}